// Round 3
// baseline (840.727 us; speedup 1.0000x reference)
//
#include <hip/hip_runtime.h>
#include <hip/hip_bf16.h>
#include <cstdint>
#include <cstddef>

// Problem constants (match reference)
#define B_TOT   2048
#define N_LIN   64
#define D_DIM   256
#define NSTEPS  4      // n_recurs + 1
#define BT      32     // batch rows per block (32 KB LDS -> 4 blocks/CU)

typedef __attribute__((ext_vector_type(8))) short short8;   // 8 bf16 = 4 VGPR
typedef __attribute__((ext_vector_type(4))) float f32x4;    // MFMA accumulator

// Split fp32 -> bf16 hi + bf16 lo (RNE both).  hi+lo reproduces f to ~2^-17 rel.
__device__ __forceinline__ void split2(float f, unsigned short& h, unsigned short& l) {
    unsigned u = __float_as_uint(f);
    unsigned r = u + 0x7FFFu + ((u >> 16) & 1u);
    h = (unsigned short)(r >> 16);
    float hf = __uint_as_float(r & 0xFFFF0000u);
    float rem = f - hf;
    unsigned u2 = __float_as_uint(rem);
    unsigned r2 = u2 + 0x7FFFu + ((u2 >> 16) & 1u);
    l = (unsigned short)(r2 >> 16);
}

__device__ __forceinline__ float bf16_to_f(unsigned short s) {
    return __uint_as_float((unsigned)s << 16);
}

// XOR-swizzled LDS index: logical (row r, col c) -> physical ushort index.
// Swizzle 16-B chunks: chunk ^= (r&7).  Conflict-free b128 A-reads.
__device__ __forceinline__ int swz(int r, int c) {
    return r * 256 + ((((c >> 3) ^ (r & 7))) << 3) + (c & 7);
}

// ---------------------------------------------------------------------------
// Prep (fast path): masked weights -> bf16 hi/lo split arrays in d_ws.
// ---------------------------------------------------------------------------
__global__ void prep_kernel(const float* __restrict__ w, const float* __restrict__ wm,
                            unsigned short* __restrict__ w_hi,
                            unsigned short* __restrict__ w_lo) {
    const int nW4 = N_LIN * D_DIM * D_DIM / 4;   // 1,048,576 float4 groups
    int stride = gridDim.x * blockDim.x;
    for (int i = blockIdx.x * blockDim.x + threadIdx.x; i < nW4; i += stride) {
        float4 wv = ((const float4*)w)[i];
        float4 mv = ((const float4*)wm)[i];
        ushort4 h, l;
        split2(wv.x * mv.x, h.x, l.x);
        split2(wv.y * mv.y, h.y, l.y);
        split2(wv.z * mv.z, h.z, l.z);
        split2(wv.w * mv.w, h.w, l.w);
        ((ushort4*)w_hi)[i] = h;
        ((ushort4*)w_lo)[i] = l;
    }
}

// ---------------------------------------------------------------------------
// Fused 4-step recurrence.  One block = 32 batch rows x one linear n.
// x in LDS as bf16 hi/lo (swizzled, 32 KB); each wave owns j-tiles
// {wv, wv+4, wv+8, wv+12} (interleaved so mask-trimmed tiles balance).
// Per wave: 2 row-tiles x 4 col-tiles of 16x16x32 bf16 MFMA, 3 products
// (hi*hi + hi*lo + lo*hi) for ~fp32 precision.  k-loop trimmed to n_act.
// ONFLY=true: no workspace — mask+split W on the fly (correctness fallback).
// ---------------------------------------------------------------------------
template <bool ONFLY>
__global__ __launch_bounds__(256, 4)
void fused_kernel(const float* __restrict__ xin,
                  const unsigned short* __restrict__ w_hi,
                  const unsigned short* __restrict__ w_lo,
                  const float* __restrict__ wraw,
                  const float* __restrict__ braw,
                  const float* __restrict__ bmask,
                  float* __restrict__ xout) {
    __shared__ unsigned short xh[BT * 256];   // 16 KB
    __shared__ unsigned short xl[BT * 256];   // 16 KB  (total 32 KB)
    __shared__ int s_nact;

    const int tid  = threadIdx.x;
    const int lane = tid & 63;
    const int wv   = tid >> 6;      // wave id
    const int quad = lane >> 4;
    const int l16  = lane & 15;

    // XCD-aware swizzle: all batch-tiles of a given n share blockIdx%8 ->
    // each XCD's L2 holds 8 n's worth of split weights (2 MB < 4 MB).
    const int xcd = blockIdx.x & 7;
    const int j8  = blockIdx.x >> 3;         // 0..511
    const int n   = (xcd << 3) | (j8 & 7);   // 0..63
    const int bt  = j8 >> 3;                 // 0..63

    const size_t row_stride = (size_t)N_LIN * D_DIM;  // 16384 floats between batch rows
    const float* xsrc = xin  + ((size_t)bt * BT * N_LIN + n) * D_DIM;
    float*       xdst = xout + ((size_t)bt * BT * N_LIN + n) * D_DIM;

    if (tid == 0) s_nact = 0;
    __syncthreads();

    // ---- n_act from bias_mask (prefix-active per reference) ----
    {
        float bmv = bmask[n * D_DIM + tid];
        unsigned long long m = __ballot(bmv != 0.0f);
        if ((tid & 63) == 0) atomicAdd(&s_nact, __popcll(m));
    }

    // ---- initial load: global fp32 -> LDS bf16 hi/lo (coalesced float4) ----
    for (int i = tid; i < BT * (D_DIM / 4); i += 256) {
        int r = i >> 6, c4 = i & 63;
        float4 v = ((const float4*)(xsrc + (size_t)r * row_stride))[c4];
        ushort4 h, l;
        split2(v.x, h.x, l.x);
        split2(v.y, h.y, l.y);
        split2(v.z, h.z, l.z);
        split2(v.w, h.w, l.w);
        int pi = r * 256 + ((((c4 >> 1) ^ (r & 7))) << 3) + ((c4 & 1) << 2);
        *((ushort4*)&xh[pi]) = h;
        *((ushort4*)&xl[pi]) = l;
    }

    // ---- per-lane masked bias for the 4 owned j-tiles (interleaved map) ----
    float bias_r[4];
    int   jbase[4];
    #pragma unroll
    for (int ct = 0; ct < 4; ++ct) {
        jbase[ct] = (ct * 4 + wv) * 16;
        int c = jbase[ct] + l16;
        bias_r[ct] = braw[n * D_DIM + c] * bmask[n * D_DIM + c];
    }

    __syncthreads();
    const int n_act = s_nact;
    const int ktmax = (n_act + 31) >> 5;          // 4..8
    bool tact[4];
    #pragma unroll
    for (int ct = 0; ct < 4; ++ct) tact[ct] = (jbase[ct] < n_act);

    // Per-tile W row base: w[j = jbase+l16][k = kt*32 + quad*8 ..]
    const unsigned short* pbh[4];
    const unsigned short* pbl[4];
    const float*          pbw[4];
    #pragma unroll
    for (int ct = 0; ct < 4; ++ct) {
        size_t off = ((size_t)n * D_DIM + jbase[ct] + l16) * D_DIM + (size_t)quad * 8;
        pbh[ct] = w_hi + off;
        pbl[ct] = w_lo + off;
        pbw[ct] = wraw + off;
    }

    #pragma unroll 1
    for (int step = 0; step < NSTEPS; ++step) {
        f32x4 acc[2][4];
        #pragma unroll
        for (int rt = 0; rt < 2; ++rt)
            #pragma unroll
            for (int ct = 0; ct < 4; ++ct)
                acc[rt][ct] = f32x4{0.f, 0.f, 0.f, 0.f};

        #pragma unroll 2
        for (int kt = 0; kt < ktmax; ++kt) {
            // ---- B fragments ----
            short8 bh[4], bl[4];
            #pragma unroll
            for (int ct = 0; ct < 4; ++ct) {
                if (!tact[ct]) continue;
                if (!ONFLY) {
                    bh[ct] = *((const short8*)(pbh[ct] + kt * 32));
                    bl[ct] = *((const short8*)(pbl[ct] + kt * 32));
                } else {
                    const float* wp = pbw[ct] + kt * 32;
                    float4 w0 = ((const float4*)wp)[0];
                    float4 w1 = ((const float4*)wp)[1];
                    float wvv[8] = {w0.x, w0.y, w0.z, w0.w, w1.x, w1.y, w1.z, w1.w};
                    float jm = bias_r[ct] == bias_r[ct] ? 1.0f : 1.0f; // placeholder no-op
                    (void)jm;
                    #pragma unroll
                    for (int j = 0; j < 8; ++j) {
                        // mask: row active iff jbase+l16 < n_act (tact), col active iff
                        // kt*32+quad*8+j < n_act (k-trim makes partial tiles possible)
                        int kcol = kt * 32 + quad * 8 + j;
                        float mv = (kcol < n_act) ? 1.0f : 0.0f;
                        unsigned short h, l;
                        split2(wvv[j] * mv, h, l);
                        bh[ct][j] = (short)h;
                        bl[ct][j] = (short)l;
                    }
                }
            }
            // ---- A fragments (LDS, swizzled; k0 8-aligned -> single chunk) ----
            short8 ah[2], al[2];
            #pragma unroll
            for (int rt = 0; rt < 2; ++rt) {
                int m = rt * 16 + l16;
                int c0 = kt * 32 + quad * 8;
                int pi = m * 256 + ((((c0 >> 3) ^ (m & 7))) << 3);
                ah[rt] = *((const short8*)&xh[pi]);
                al[rt] = *((const short8*)&xl[pi]);
            }
            #pragma unroll
            for (int rt = 0; rt < 2; ++rt) {
                #pragma unroll
                for (int ct = 0; ct < 4; ++ct) {
                    if (!tact[ct]) continue;
                    acc[rt][ct] = __builtin_amdgcn_mfma_f32_16x16x32_bf16(ah[rt], bh[ct], acc[rt][ct], 0, 0, 0);
                    acc[rt][ct] = __builtin_amdgcn_mfma_f32_16x16x32_bf16(ah[rt], bl[ct], acc[rt][ct], 0, 0, 0);
                    acc[rt][ct] = __builtin_amdgcn_mfma_f32_16x16x32_bf16(al[rt], bh[ct], acc[rt][ct], 0, 0, 0);
                }
            }
        }

        __syncthreads();   // all waves' A-reads of x done before x is overwritten

        const bool last = (step == NSTEPS - 1);
        #pragma unroll
        for (int rt = 0; rt < 2; ++rt) {
            #pragma unroll
            for (int ct = 0; ct < 4; ++ct) {
                int c = jbase[ct] + l16;             // this lane's output column
                if (tact[ct]) {
                    #pragma unroll
                    for (int rg = 0; rg < 4; ++rg) {
                        int r = rt * 16 + quad * 4 + rg; // C/D: row = quad*4 + reg
                        int pi = swz(r, c);
                        float y   = acc[rt][ct][rg] + bias_r[ct];
                        float old = bf16_to_f(xh[pi]) + bf16_to_f(xl[pi]);
                        float xn  = old + fmaxf(y, 0.f);
                        if (last) {
                            xdst[(size_t)r * row_stride + c] = xn;
                        } else {
                            unsigned short h, l;
                            split2(xn, h, l);
                            xh[pi] = h;
                            xl[pi] = l;
                        }
                    }
                } else if (last) {
                    // inactive columns: pass original x through
                    #pragma unroll
                    for (int rg = 0; rg < 4; ++rg) {
                        int r = rt * 16 + quad * 4 + rg;
                        int pi = swz(r, c);
                        xdst[(size_t)r * row_stride + c] = bf16_to_f(xh[pi]) + bf16_to_f(xl[pi]);
                    }
                }
            }
        }
        __syncthreads();   // new x fully written before next step's A-reads
    }
}

// ---------------------------------------------------------------------------
extern "C" void kernel_launch(void* const* d_in, const int* in_sizes, int n_in,
                              void* d_out, int out_size, void* d_ws, size_t ws_size,
                              hipStream_t stream) {
    const float* x  = (const float*)d_in[0];
    const float* w  = (const float*)d_in[1];
    const float* b  = (const float*)d_in[2];
    const float* wm = (const float*)d_in[3];
    const float* bm = (const float*)d_in[4];
    float* out = (float*)d_out;

    const size_t needW = (size_t)2 * N_LIN * D_DIM * D_DIM * sizeof(unsigned short); // 16 MB
    const int grid = (B_TOT / BT) * N_LIN;   // 4096 blocks

    if (ws_size >= needW) {
        unsigned short* w_hi = (unsigned short*)d_ws;
        unsigned short* w_lo = w_hi + (size_t)N_LIN * D_DIM * D_DIM;
        prep_kernel<<<2048, 256, 0, stream>>>(w, wm, w_hi, w_lo);
        fused_kernel<false><<<grid, 256, 0, stream>>>(x, w_hi, w_lo, w, b, bm, out);
    } else {
        fused_kernel<true><<<grid, 256, 0, stream>>>(x, nullptr, nullptr, w, b, bm, out);
    }
}